// Round 21
// baseline (124.509 us; speedup 1.0000x reference)
//
#include <hip/hip_runtime.h>
#include <hip/hip_bf16.h>
#include <math.h>

namespace {

constexpr int D  = 128;
constexpr int TN = 64;
constexpr int NB = 8;     // batches per fused block

typedef _Float16 h2  __attribute__((ext_vector_type(2)));
typedef _Float16 v8h __attribute__((ext_vector_type(8)));
typedef float    v4f __attribute__((ext_vector_type(4)));
typedef unsigned uv4 __attribute__((ext_vector_type(4)));

__device__ __forceinline__ unsigned pack_h2(float a, float b) {
    h2 v; v.x = (_Float16)a; v.y = (_Float16)b;
    return __builtin_bit_cast(unsigned, v);
}
__device__ __forceinline__ float2 unp_h2(unsigned u) {
    h2 v = __builtin_bit_cast(h2, u);
    return make_float2((float)v.x, (float)v.y);
}
__device__ __forceinline__ float fdot2f(unsigned a, unsigned b, float c) {
#if __has_builtin(__builtin_amdgcn_fdot2)
    return __builtin_amdgcn_fdot2(__builtin_bit_cast(h2, a),
                                  __builtin_bit_cast(h2, b), c, false);
#else
    const float2 fa = unp_h2(a), fb = unp_h2(b);
    return fmaf(fa.x, fb.x, fmaf(fa.y, fb.y, c));
#endif
}
__device__ __forceinline__ int rot32(int fc) { return ((fc & 7) << 2) | (fc >> 3); }
__device__ __forceinline__ v8h as_h8(uv4 u) { return __builtin_bit_cast(v8h, u); }

// d_ws layout:
//   NT [1024 cols][128 k] f16  (N^T, k-major 8-groups)  256 KB
//   MT [128 e][1024 k]   f16  (M^T, k-major 8-groups)  256 KB

// ---------------- K0: precompute NT and MT (transposed, f16, k-grouped-by-8) -------------
__global__ __launch_bounds__(256)
void k0_nm(const float* __restrict__ WQ, const float* __restrict__ WK,
           const float* __restrict__ WV, const float* __restrict__ WO,
           unsigned* __restrict__ NT, unsigned* __restrict__ MT)
{
    const int t = blockIdx.x * 256 + threadIdx.x;   // 0..16383
    {   // NT[col][k8*8..+8]: col = h*128+d;  N[k][col] = 0.25 * WQ[k]·WK[d] (head h block)
        const int col = t >> 4, k8 = t & 15;
        const int h = col >> 7, d = col & 127;
        const float* wk = WK + (size_t)d * D + h * 16;
        float a[8];
        #pragma unroll
        for (int jj = 0; jj < 8; ++jj) {
            const int k = k8 * 8 + jj;
            const float* wq = WQ + (size_t)k * D + h * 16;
            float s = 0.f;
            #pragma unroll
            for (int j = 0; j < 16; ++j) s = fmaf(wq[j], wk[j], s);
            a[jj] = 0.25f * s;
        }
        uv4 o;
        o[0] = pack_h2(a[0], a[1]); o[1] = pack_h2(a[2], a[3]);
        o[2] = pack_h2(a[4], a[5]); o[3] = pack_h2(a[6], a[7]);
        ((uv4*)NT)[col * 16 + k8] = o;
    }
    {   // MT[e][k8*8..+8]: k = h*128+d;  M[k][e] = WV[d]·WO[:,e] (head h block)
        const int e = t >> 7, k8 = t & 127;
        const int h = k8 >> 4, d0 = (k8 * 8) & 127;
        const float* wo = WO + (size_t)(h * 16) * D + e;
        float b[8];
        #pragma unroll
        for (int jj = 0; jj < 8; ++jj) {
            const float* wv = WV + (size_t)(d0 + jj) * D + h * 16;
            float s = 0.f;
            #pragma unroll
            for (int j = 0; j < 16; ++j) s = fmaf(wv[j], wo[(size_t)j * D], s);
            b[jj] = s;
        }
        uv4 o;
        o[0] = pack_h2(b[0], b[1]); o[1] = pack_h2(b[2], b[3]);
        o[2] = pack_h2(b[4], b[5]); o[3] = pack_h2(b[6], b[7]);
        ((uv4*)MT)[e * 128 + k8] = o;
    }
}

// ---------------- fused: qk=MFMA(NT,c) -> 8x attention (r20 body) -> out=MFMA(MT,s) -------
// LDS ~37.5 KB -> 4 blocks/CU. Attention loop byte-identical to r20 (proven).
__global__ __launch_bounds__(256, 2)
void k_fused(const float* __restrict__ center, const float* __restrict__ neighbors,
             const unsigned* __restrict__ NT, const unsigned* __restrict__ MT,
             float* __restrict__ out)
{
    __shared__ __align__(16) float nb_lds[TN * D / 2];  // 16 KB f16 tokens; uint2 slot (t<<5)|(fc^(t&7))
    __shared__ __align__(16) float qs8f[NB * 512];      // 16 KB f16: qk (rotated) -> s (k-paired linear)
    __shared__ __align__(16) unsigned c2u[NB * 64];     // 2 KB f16 k-paired center rows
    __shared__ float P_lds[TN * 12];                    // 3 KB
    __shared__ float red_pc[8];

    const int tid = threadIdx.x;           // 0..255
    const int w   = tid >> 6;              // wave 0..3
    const int l   = tid & 63;
    const size_t rb = (size_t)blockIdx.x * NB;

    uint2* nbu  = (uint2*)nb_lds;
    uint2* qs8u = (uint2*)qs8f;

    // ---- stage c2 (k-paired f16) ----
    {
        const int r = tid >> 5, f = tid & 31;
        const float4 g = ((const float4*)(center + (rb + r) * (size_t)D))[f];
        c2u[r * 64 + 2 * f]     = pack_h2(g.x, g.y);
        c2u[r * 64 + 2 * f + 1] = pack_h2(g.z, g.w);
    }
    __syncthreads();                       // c2 visible

    // ================= k1-part: qk^T = NT @ c^T via MFMA 16x16x32 f16 =================
    // Wave w owns d-tiles w*16..w*16+15 (16 rows of qk-dim each). N-dim = 16 batch slots
    // (8 real). C/D layout (m89): col=lane&15=batch, row=(lane>>4)*4+reg = d-in-tile.
    {
        const uv4* NTv = (const uv4*)NT;
        const uv4* cbv = (const uv4*)c2u;
        uv4 bfr[4];
        #pragma unroll
        for (int kk = 0; kk < 4; ++kk)      // B frags: c[batch l&7][k-slots (l>>4)*8+kk*32..]
            bfr[kk] = cbv[(l & 7) * 16 + kk * 4 + (l >> 4)];

        #pragma unroll 2
        for (int t = 0; t < 16; ++t) {
            const int col = (w * 16 + t) * 16 + (l & 15);   // qk-dim index for A
            v4f acc = {0.f, 0.f, 0.f, 0.f};
            #pragma unroll
            for (int kk = 0; kk < 4; ++kk) {
                const uv4 av = NTv[col * 16 + kk * 4 + (l >> 4)];
                acc = __builtin_amdgcn_mfma_f32_16x16x32_f16(as_h8(av), as_h8(bfr[kk]), acc, 0, 0, 0);
            }
            const int batch = l & 15;
            if (batch < NB) {
                const int d0 = (w * 16 + t) * 16 + (l >> 4) * 4;   // 4 consecutive qk cols
                const int h = d0 >> 7, fc = (d0 & 127) >> 2;
                qs8u[batch * 256 + h * 32 + rot32(fc)] =
                    make_uint2(pack_h2(acc[0], acc[1]), pack_h2(acc[2], acc[3]));
            }
        }
    }

    // ---- load batch-0 nb into staging regs (after GEMM: r18 liveness rule) ----
    float4 st[8];
    {
        const float4* g0 = (const float4*)(neighbors + rb * TN * D);
        #pragma unroll
        for (int i = 0; i < 8; ++i) st[i] = g0[i * 256 + tid];
    }
    __syncthreads();                       // qk visible

    // ================= per-batch attention loop (r20-proven body, UNCHANGED) =================
    #pragma unroll 1
    for (int bb = 0; bb < NB; ++bb) {
        #pragma unroll
        for (int i = 0; i < 8; ++i) {
            const int fi = i * 256 + tid;
            const int t  = fi >> 5;
            const int fc = fi & 31;
            nbu[(t << 5) | (fc ^ (t & 7))] =
                make_uint2(pack_h2(st[i].x, st[i].y), pack_h2(st[i].z, st[i].w));
        }
        __syncthreads();                   // nb staged

        if (bb + 1 < NB) {
            const float4* gn = (const float4*)(neighbors + (rb + bb + 1) * TN * D);
            #pragma unroll
            for (int i = 0; i < 8; ++i) st[i] = gn[i * 256 + tid];
        }

        const uint2*    nb2 = (const uint2*)nb_lds;
        const uint2*    qku = qs8u + bb * 256;
        const unsigned* cb2 = c2u + bb * 64;

        const int tg = l & 15;
        const int q  = l >> 4;
        const int h0 = 2 * w;

        float sc0[4] = {0.f, 0.f, 0.f, 0.f};
        float sc1[4] = {0.f, 0.f, 0.f, 0.f};
        float s0a = 0.f, s0b = 0.f;
        #pragma unroll
        for (int jj = 0; jj < 8; ++jj) {
            const int rfc = (jj << 2) | q;
            const int fc  = (q << 3) | jj;
            const uint2 kv0p = qku[h0 * 32 + rfc];
            const uint2 kv1p = qku[(h0 + 1) * 32 + rfc];
            const unsigned cpa = cb2[2 * fc], cpb = cb2[2 * fc + 1];
            s0a = fdot2f(cpa, kv0p.x, fdot2f(cpb, kv0p.y, s0a));
            s0b = fdot2f(cpa, kv1p.x, fdot2f(cpb, kv1p.y, s0b));
            #pragma unroll
            for (int k = 0; k < 4; ++k) {
                const int t = tg + (k << 4);
                const uint2 u = nb2[(t << 5) | (fc ^ (t & 7))];
                sc0[k] = fdot2f(u.x, kv0p.x, fdot2f(u.y, kv0p.y, sc0[k]));
                sc1[k] = fdot2f(u.x, kv1p.x, fdot2f(u.y, kv1p.y, sc1[k]));
            }
        }
        #pragma unroll
        for (int k = 0; k < 4; ++k) {
            sc0[k] += __shfl_xor(sc0[k], 16);  sc0[k] += __shfl_xor(sc0[k], 32);
            sc1[k] += __shfl_xor(sc1[k], 16);  sc1[k] += __shfl_xor(sc1[k], 32);
        }
        s0a += __shfl_xor(s0a, 16);  s0a += __shfl_xor(s0a, 32);
        s0b += __shfl_xor(s0b, 16);  s0b += __shfl_xor(s0b, 32);

        float m0 = fmaxf(fmaxf(sc0[0], sc0[1]), fmaxf(sc0[2], sc0[3]));
        float m1 = fmaxf(fmaxf(sc1[0], sc1[1]), fmaxf(sc1[2], sc1[3]));
        #pragma unroll
        for (int off = 8; off >= 1; off >>= 1) {
            m0 = fmaxf(m0, __shfl_xor(m0, off));
            m1 = fmaxf(m1, __shfl_xor(m1, off));
        }
        m0 = fmaxf(m0, s0a);
        m1 = fmaxf(m1, s0b);
        float e0v[4], e1v[4];
        float sum0 = 0.f, sum1 = 0.f;
        #pragma unroll
        for (int k = 0; k < 4; ++k) {
            e0v[k] = __expf(sc0[k] - m0);  sum0 += e0v[k];
            e1v[k] = __expf(sc1[k] - m1);  sum1 += e1v[k];
        }
        #pragma unroll
        for (int off = 8; off >= 1; off >>= 1) {
            sum0 += __shfl_xor(sum0, off);
            sum1 += __shfl_xor(sum1, off);
        }
        const float ec0 = __expf(s0a - m0);
        const float ec1 = __expf(s0b - m1);
        const float inv0 = 1.0f / (sum0 + ec0);
        const float inv1 = 1.0f / (sum1 + ec1);
        if (q == 0) {
            #pragma unroll
            for (int k = 0; k < 4; ++k) {
                const int t = tg + (k << 4);
                *reinterpret_cast<float2*>(&P_lds[t * 12 + h0]) =
                    make_float2(e0v[k] * inv0, e1v[k] * inv1);
            }
            if (tg == 0) {
                red_pc[h0]     = ec0 * inv0;
                red_pc[h0 + 1] = ec1 * inv1;
            }
        }
        __syncthreads();   // bar: P complete

        const int hl  = l >> 5;
        const int fc2 = l & 31;
        float4 pacc[4];
        #pragma unroll
        for (int j = 0; j < 4; ++j) pacc[j] = make_float4(0.f, 0.f, 0.f, 0.f);
        #pragma unroll
        for (int tt = 0; tt < 16; ++tt) {
            const int t = w * 16 + tt;
            const uint2 u = nb2[(t << 5) | (fc2 ^ (t & 7))];
            const float2 ta = unp_h2(u.x), tb = unp_h2(u.y);
            const float t0 = ta.x, t1 = ta.y, t2 = tb.x, t3 = tb.y;
            const float4 pv = ((const float4*)P_lds)[t * 3 + hl];
            pacc[0].x = fmaf(pv.x, t0, pacc[0].x); pacc[0].y = fmaf(pv.x, t1, pacc[0].y);
            pacc[0].z = fmaf(pv.x, t2, pacc[0].z); pacc[0].w = fmaf(pv.x, t3, pacc[0].w);
            pacc[1].x = fmaf(pv.y, t0, pacc[1].x); pacc[1].y = fmaf(pv.y, t1, pacc[1].y);
            pacc[1].z = fmaf(pv.y, t2, pacc[1].z); pacc[1].w = fmaf(pv.y, t3, pacc[1].w);
            pacc[2].x = fmaf(pv.z, t0, pacc[2].x); pacc[2].y = fmaf(pv.z, t1, pacc[2].y);
            pacc[2].z = fmaf(pv.z, t2, pacc[2].z); pacc[2].w = fmaf(pv.z, t3, pacc[2].w);
            pacc[3].x = fmaf(pv.w, t0, pacc[3].x); pacc[3].y = fmaf(pv.w, t1, pacc[3].y);
            pacc[3].z = fmaf(pv.w, t2, pacc[3].z); pacc[3].w = fmaf(pv.w, t3, pacc[3].w);
        }
        #pragma unroll
        for (int j = 0; j < 4; ++j)
            ((float4*)nb_lds)[w * 256 + (hl * 4 + j) * 32 + fc2] = pacc[j];
        __syncthreads();   // bar: partials ready

        {
            const int hE = tid >> 5;
            const int fE = tid & 31;
            float4 sum = make_float4(0.f, 0.f, 0.f, 0.f);
            #pragma unroll
            for (int ww = 0; ww < 4; ++ww) {
                const float4 p = ((const float4*)nb_lds)[ww * 256 + hE * 32 + fE];
                sum.x += p.x; sum.y += p.y; sum.z += p.z; sum.w += p.w;
            }
            const float pc = red_pc[hE];
            const float2 ca = unp_h2(cb2[2 * fE]), cb = unp_h2(cb2[2 * fE + 1]);
            sum.x = fmaf(pc, ca.x, sum.x);
            sum.y = fmaf(pc, ca.y, sum.y);
            sum.z = fmaf(pc, cb.x, sum.z);
            sum.w = fmaf(pc, cb.y, sum.w);
            qs8u[bb * 256 + tid] =
                make_uint2(pack_h2(sum.x, sum.y), pack_h2(sum.z, sum.w));
        }
        __syncthreads();   // bar: s visible; next commit may overwrite nb
    }

    // ================= k3-part: out^T = MT @ s^T via MFMA 16x16x32 f16 =================
    // Wave w owns e-tiles 2w, 2w+1. K=1024 in 32 steps. Direct float4 global stores.
    {
        const uv4* MTv = (const uv4*)MT;
        const uv4* spv = (const uv4*)qs8f;
        v4f acc0 = {0.f, 0.f, 0.f, 0.f};
        v4f acc1 = {0.f, 0.f, 0.f, 0.f};
        const int ec0 = (2 * w) * 16 + (l & 15);
        const int ec1 = (2 * w + 1) * 16 + (l & 15);

        #pragma unroll 2
        for (int step = 0; step < 32; ++step) {
            const uv4 bv = spv[(l & 7) * 128 + step * 4 + (l >> 4)];   // s[batch][k-slots]
            const uv4 a0 = MTv[ec0 * 128 + step * 4 + (l >> 4)];
            const uv4 a1 = MTv[ec1 * 128 + step * 4 + (l >> 4)];
            acc0 = __builtin_amdgcn_mfma_f32_16x16x32_f16(as_h8(a0), as_h8(bv), acc0, 0, 0, 0);
            acc1 = __builtin_amdgcn_mfma_f32_16x16x32_f16(as_h8(a1), as_h8(bv), acc1, 0, 0, 0);
        }
        const int batch = l & 15;
        if (batch < NB) {
            const int e0 = (2 * w) * 16 + (l >> 4) * 4;
            const int e1 = (2 * w + 1) * 16 + (l >> 4) * 4;
            float* orow = out + (rb + batch) * (size_t)D;
            *reinterpret_cast<float4*>(orow + e0) = make_float4(acc0[0], acc0[1], acc0[2], acc0[3]);
            *reinterpret_cast<float4*>(orow + e1) = make_float4(acc1[0], acc1[1], acc1[2], acc1[3]);
        }
    }
}

} // namespace

extern "C" void kernel_launch(void* const* d_in, const int* in_sizes, int n_in,
                              void* d_out, int out_size, void* d_ws, size_t ws_size,
                              hipStream_t stream) {
    const float* center    = (const float*)d_in[0];
    const float* neighbors = (const float*)d_in[1];
    const float* WQ        = (const float*)d_in[2];
    const float* WK        = (const float*)d_in[3];
    const float* WV        = (const float*)d_in[4];
    const float* WO        = (const float*)d_in[5];
    float* outp            = (float*)d_out;

    const int B = in_sizes[0] / D;   // 8192

    unsigned* NT = (unsigned*)d_ws;          // 1024*64 uint (256 KB)
    unsigned* MT = NT + 1024 * 64;           // 128*512 uint (256 KB)

    hipLaunchKernelGGL(k0_nm,   dim3(64),     dim3(256), 0, stream, WQ, WK, WV, WO, NT, MT);
    hipLaunchKernelGGL(k_fused, dim3(B / NB), dim3(256), 0, stream, center, neighbors, NT, MT, outp);
}

// Round 22
// 102.214 us; speedup vs baseline: 1.2181x; 1.2181x over previous
//
#include <hip/hip_runtime.h>
#include <hip/hip_bf16.h>
#include <math.h>

namespace {

constexpr int D  = 128;
constexpr int TN = 64;
constexpr int NB = 8;     // batches per fused block

typedef _Float16 h2 __attribute__((ext_vector_type(2)));

__device__ __forceinline__ unsigned pack_h2(float a, float b) {
    h2 v; v.x = (_Float16)a; v.y = (_Float16)b;
    return __builtin_bit_cast(unsigned, v);
}
__device__ __forceinline__ float2 unp_h2(unsigned u) {
    h2 v = __builtin_bit_cast(h2, u);
    return make_float2((float)v.x, (float)v.y);
}
__device__ __forceinline__ h2 bch2(unsigned u) { return __builtin_bit_cast(h2, u); }
__device__ __forceinline__ float fdot2f(unsigned a, unsigned b, float c) {
#if __has_builtin(__builtin_amdgcn_fdot2)
    return __builtin_amdgcn_fdot2(__builtin_bit_cast(h2, a),
                                  __builtin_bit_cast(h2, b), c, false);
#else
    const float2 fa = unp_h2(a), fb = unp_h2(b);
    return fmaf(fa.x, fb.x, fmaf(fa.y, fb.y, c));
#endif
}

// d_ws layout (both k-paired f16):
//   N2 [64][1024]  uint (pairs over k of N[128][1024])   256 KB
//   M2 [512][128]  uint (pairs over k of M[1024][128])   256 KB

// ---------------- K0: precompute N2 and M2 (k-paired f16, r20-proven) ----------------
__global__ __launch_bounds__(256)
void k0_nm(const float* __restrict__ WQ, const float* __restrict__ WK,
           const float* __restrict__ WV, const float* __restrict__ WO,
           unsigned* __restrict__ N2, unsigned* __restrict__ M2)
{
    const int t = blockIdx.x * 256 + threadIdx.x;   // 0..65535
    {   // N2[kk][col]: pair of N[2kk][col], N[2kk+1][col]
        const int kk = t >> 10, col = t & 1023;
        const int h = col >> 7, d = col & 127;
        const float* wq0 = WQ + (size_t)(2 * kk) * D + h * 16;
        const float* wq1 = wq0 + D;
        const float* wk  = WK + (size_t)d * D + h * 16;
        float a0 = 0.f, a1 = 0.f;
        #pragma unroll
        for (int j = 0; j < 16; ++j) {
            a0 = fmaf(wq0[j], wk[j], a0);
            a1 = fmaf(wq1[j], wk[j], a1);
        }
        N2[t] = pack_h2(0.25f * a0, 0.25f * a1);
    }
    {   // M2[kk][e]: pair of M[2kk][e], M[2kk+1][e];  k = h*128+d
        const int kk = t >> 7, e = t & 127;
        const int k0 = 2 * kk;
        const int h = k0 >> 7, d = k0 & 127;
        const float* wv0 = WV + (size_t)d * D + h * 16;
        const float* wv1 = wv0 + D;
        const float* wo  = WO + (size_t)(h * 16) * D + e;
        float b0 = 0.f, b1 = 0.f;
        #pragma unroll
        for (int j = 0; j < 16; ++j) {
            const float w_ = wo[(size_t)j * D];
            b0 = fmaf(wv0[j], w_, b0);
            b1 = fmaf(wv1[j], w_, b1);
        }
        M2[t] = pack_h2(b0, b1);
    }
}

// ---------------- fused: qk=c@N2 -> 8x attention -> out=s@M2 (r20 + pk_fma phase D) -------
// LDS ~37.9 KB -> 4 blocks/CU.
__global__ __launch_bounds__(256, 2)
void k_fused(const float* __restrict__ center, const float* __restrict__ neighbors,
             const unsigned* __restrict__ N2, const unsigned* __restrict__ M2,
             float* __restrict__ out)
{
    __shared__ __align__(16) float nb_lds[TN * D / 2];  // 16 KB f16 tokens; uint2 slot (t<<5)|(fc^(t&7))
    __shared__ __align__(16) float qs8f[NB * 512];      // 16 KB f16: qk (rotated) -> s (k-paired linear)
    __shared__ __align__(16) unsigned c2u[NB * 64];     // 2 KB f16 k-paired center rows
    __shared__ __align__(16) unsigned Pu[TN * 12];      // 3 KB: P as duplicated f16 pairs {p,p}
    __shared__ float red_pc[8];

    const int tid = threadIdx.x;           // 0..255
    const int w   = tid >> 6;              // wave 0..3 (attention: owns heads 2w,2w+1)
    const int l   = tid & 63;
    const size_t rb = (size_t)blockIdx.x * NB;

    uint2* nbu  = (uint2*)nb_lds;
    uint2* qs8u = (uint2*)qs8f;

    // ---- stage c2 (k-paired f16) ----
    {
        const int r = tid >> 5, f = tid & 31;
        const float4 g = ((const float4*)(center + (rb + r) * (size_t)D))[f];
        c2u[r * 64 + 2 * f]     = pack_h2(g.x, g.y);
        c2u[r * 64 + 2 * f + 1] = pack_h2(g.z, g.w);
    }
    __syncthreads();                       // c2 visible

    // ================= k1-part: qk8 = c @ N (fdot2, k-paired, r20-proven) =================
    {
        const uint4* N2u4 = (const uint4*)N2;   // row kk = 256 uint4
        float4 acc[NB];
        #pragma unroll
        for (int r = 0; r < NB; ++r) acc[r] = make_float4(0.f, 0.f, 0.f, 0.f);

        #pragma unroll 4
        for (int kk = 0; kk < 64; ++kk) {
            const uint4 u = N2u4[(size_t)kk * 256 + tid];   // 4 cols' k-pair
            #pragma unroll
            for (int r = 0; r < NB; ++r) {
                const unsigned cp = c2u[r * 64 + kk];       // broadcast
                acc[r].x = fdot2f(cp, u.x, acc[r].x);
                acc[r].y = fdot2f(cp, u.y, acc[r].y);
                acc[r].z = fdot2f(cp, u.z, acc[r].z);
                acc[r].w = fdot2f(cp, u.w, acc[r].w);
            }
        }
        const int fc = tid & 31;
        const int qslot = (tid & ~31) | (((fc & 7) << 2) | (fc >> 3));  // rotated qk layout
        #pragma unroll
        for (int r = 0; r < NB; ++r)
            qs8u[r * 256 + qslot] =
                make_uint2(pack_h2(acc[r].x, acc[r].y), pack_h2(acc[r].z, acc[r].w));
    }

    // ---- NOW load batch-0 nb into staging regs (not live across the GEMM above) ----
    float4 st[8];
    {
        const float4* g0 = (const float4*)(neighbors + rb * TN * D);
        #pragma unroll
        for (int i = 0; i < 8; ++i) st[i] = g0[i * 256 + tid];
    }
    __syncthreads();                       // qk visible

    // ================= per-batch attention loop =================
    #pragma unroll 1
    for (int bb = 0; bb < NB; ++bb) {
        // ---- commit staged nb registers -> f16 swizzled LDS ----
        #pragma unroll
        for (int i = 0; i < 8; ++i) {
            const int fi = i * 256 + tid;
            const int t  = fi >> 5;
            const int fc = fi & 31;
            nbu[(t << 5) | (fc ^ (t & 7))] =
                make_uint2(pack_h2(st[i].x, st[i].y), pack_h2(st[i].z, st[i].w));
        }
        __syncthreads();                   // nb staged

        // ---- issue next batch's nb loads; they fly during phases A-E ----
        if (bb + 1 < NB) {
            const float4* gn = (const float4*)(neighbors + (rb + bb + 1) * TN * D);
            #pragma unroll
            for (int i = 0; i < 8; ++i) st[i] = gn[i * 256 + tid];
        }

        const uint2*    nb2 = (const uint2*)nb_lds;
        const uint2*    qku = qs8u + bb * 256;
        const unsigned* cb2 = c2u + bb * 64;

        // ---- phase A: wave w scores all 64 tokens for heads 2w,2w+1; wave-local softmax ----
        const int tg = l & 15;
        const int q  = l >> 4;
        const int h0 = 2 * w;

        float sc0[4] = {0.f, 0.f, 0.f, 0.f};
        float sc1[4] = {0.f, 0.f, 0.f, 0.f};
        float s0a = 0.f, s0b = 0.f;
        #pragma unroll
        for (int jj = 0; jj < 8; ++jj) {
            const int rfc = (jj << 2) | q;     // rotated slot of fc=(q<<3)|jj
            const int fc  = (q << 3) | jj;
            const uint2 kv0p = qku[h0 * 32 + rfc];
            const uint2 kv1p = qku[(h0 + 1) * 32 + rfc];
            const unsigned cpa = cb2[2 * fc], cpb = cb2[2 * fc + 1];
            s0a = fdot2f(cpa, kv0p.x, fdot2f(cpb, kv0p.y, s0a));
            s0b = fdot2f(cpa, kv1p.x, fdot2f(cpb, kv1p.y, s0b));
            #pragma unroll
            for (int k = 0; k < 4; ++k) {
                const int t = tg + (k << 4);
                const uint2 u = nb2[(t << 5) | (fc ^ (t & 7))];
                sc0[k] = fdot2f(u.x, kv0p.x, fdot2f(u.y, kv0p.y, sc0[k]));
                sc1[k] = fdot2f(u.x, kv1p.x, fdot2f(u.y, kv1p.y, sc1[k]));
            }
        }
        #pragma unroll
        for (int k = 0; k < 4; ++k) {
            sc0[k] += __shfl_xor(sc0[k], 16);  sc0[k] += __shfl_xor(sc0[k], 32);
            sc1[k] += __shfl_xor(sc1[k], 16);  sc1[k] += __shfl_xor(sc1[k], 32);
        }
        s0a += __shfl_xor(s0a, 16);  s0a += __shfl_xor(s0a, 32);
        s0b += __shfl_xor(s0b, 16);  s0b += __shfl_xor(s0b, 32);

        float m0 = fmaxf(fmaxf(sc0[0], sc0[1]), fmaxf(sc0[2], sc0[3]));
        float m1 = fmaxf(fmaxf(sc1[0], sc1[1]), fmaxf(sc1[2], sc1[3]));
        #pragma unroll
        for (int off = 8; off >= 1; off >>= 1) {
            m0 = fmaxf(m0, __shfl_xor(m0, off));
            m1 = fmaxf(m1, __shfl_xor(m1, off));
        }
        m0 = fmaxf(m0, s0a);
        m1 = fmaxf(m1, s0b);
        float e0v[4], e1v[4];
        float sum0 = 0.f, sum1 = 0.f;
        #pragma unroll
        for (int k = 0; k < 4; ++k) {
            e0v[k] = __expf(sc0[k] - m0);  sum0 += e0v[k];
            e1v[k] = __expf(sc1[k] - m1);  sum1 += e1v[k];
        }
        #pragma unroll
        for (int off = 8; off >= 1; off >>= 1) {
            sum0 += __shfl_xor(sum0, off);
            sum1 += __shfl_xor(sum1, off);
        }
        const float ec0 = __expf(s0a - m0);
        const float ec1 = __expf(s0b - m1);
        const float inv0 = 1.0f / (sum0 + ec0);
        const float inv1 = 1.0f / (sum1 + ec1);
        if (q == 0) {
            #pragma unroll
            for (int k = 0; k < 4; ++k) {
                const int t = tg + (k << 4);
                const float p0 = e0v[k] * inv0;
                const float p1 = e1v[k] * inv1;
                // duplicated-f16 P pairs: one uint2 write per token for this wave's 2 heads
                *reinterpret_cast<uint2*>(&Pu[t * 12 + h0]) =
                    make_uint2(pack_h2(p0, p0), pack_h2(p1, p1));
            }
            if (tg == 0) {
                red_pc[h0]     = ec0 * inv0;
                red_pc[h0 + 1] = ec1 * inv1;
            }
        }
        __syncthreads();   // bar: P complete

        // ---- phase D (pk_fma): wave w sums its 16 tokens; lane = (h-half, f4 col) ----
        const int hl  = l >> 5;
        const int fc2 = l & 31;
        h2 pk00 = {0, 0}, pk01 = {0, 0};   // head hl*4+0: d01, d23
        h2 pk10 = {0, 0}, pk11 = {0, 0};
        h2 pk20 = {0, 0}, pk21 = {0, 0};
        h2 pk30 = {0, 0}, pk31 = {0, 0};
        #pragma unroll
        for (int tt = 0; tt < 16; ++tt) {
            const int t = w * 16 + tt;
            const uint2 u = nb2[(t << 5) | (fc2 ^ (t & 7))];
            const h2 u0 = bch2(u.x), u1 = bch2(u.y);
            const uint4 pp = *reinterpret_cast<const uint4*>(&Pu[t * 12 + hl * 4]);
            const h2 p0 = bch2(pp.x), p1 = bch2(pp.y), p2 = bch2(pp.z), p3 = bch2(pp.w);
            pk00 += p0 * u0;  pk01 += p0 * u1;
            pk10 += p1 * u0;  pk11 += p1 * u1;
            pk20 += p2 * u0;  pk21 += p2 * u1;
            pk30 += p3 * u0;  pk31 += p3 * u1;
        }
        // convert packed partials -> f32, overlay the wave's OWN dead f16 token rows
        {
            float4 pf;
            pf = make_float4((float)pk00.x, (float)pk00.y, (float)pk01.x, (float)pk01.y);
            ((float4*)nb_lds)[w * 256 + (hl * 4 + 0) * 32 + fc2] = pf;
            pf = make_float4((float)pk10.x, (float)pk10.y, (float)pk11.x, (float)pk11.y);
            ((float4*)nb_lds)[w * 256 + (hl * 4 + 1) * 32 + fc2] = pf;
            pf = make_float4((float)pk20.x, (float)pk20.y, (float)pk21.x, (float)pk21.y);
            ((float4*)nb_lds)[w * 256 + (hl * 4 + 2) * 32 + fc2] = pf;
            pf = make_float4((float)pk30.x, (float)pk30.y, (float)pk31.x, (float)pk31.y);
            ((float4*)nb_lds)[w * 256 + (hl * 4 + 3) * 32 + fc2] = pf;
        }
        __syncthreads();   // bar: partials ready

        // ---- phase E: combine partials + center seed; write s (f16 k-paired, linear) ----
        {
            const int hE = tid >> 5;
            const int fE = tid & 31;
            float4 sum = make_float4(0.f, 0.f, 0.f, 0.f);
            #pragma unroll
            for (int ww = 0; ww < 4; ++ww) {
                const float4 p = ((const float4*)nb_lds)[ww * 256 + hE * 32 + fE];
                sum.x += p.x; sum.y += p.y; sum.z += p.z; sum.w += p.w;
            }
            const float pc = red_pc[hE];
            const float2 ca = unp_h2(cb2[2 * fE]), cb = unp_h2(cb2[2 * fE + 1]);
            sum.x = fmaf(pc, ca.x, sum.x);
            sum.y = fmaf(pc, ca.y, sum.y);
            sum.z = fmaf(pc, cb.x, sum.z);
            sum.w = fmaf(pc, cb.y, sum.w);
            qs8u[bb * 256 + tid] =
                make_uint2(pack_h2(sum.x, sum.y), pack_h2(sum.z, sum.w));
        }
        __syncthreads();   // bar: partials consumed; next commit may overwrite nb
    }

    // ================= k3-part: out = s @ M (fdot2, k-paired, r20-proven) =================
    {
        const int cg = tid & 31;
        const int kg = tid >> 5;
        const int c4i = cg << 2;
        const int kb2 = kg << 6;           // kk base (64 pairs per k-split group)

        float4 acc[NB];
        #pragma unroll
        for (int r = 0; r < NB; ++r) acc[r] = make_float4(0.f, 0.f, 0.f, 0.f);

        const uint4* M2u4 = (const uint4*)M2;           // row kk = 32 uint4
        const unsigned* sp2 = (const unsigned*)qs8f;    // s pairs: [r*512 + kk]

        #pragma unroll 4
        for (int k2 = 0; k2 < 64; ++k2) {
            const int kk = kb2 + k2;
            const uint4 u = M2u4[(size_t)kk * 32 + cg];
            #pragma unroll
            for (int r = 0; r < NB; ++r) {
                const unsigned sv = sp2[r * 512 + kk];  // broadcast
                acc[r].x = fdot2f(sv, u.x, acc[r].x);
                acc[r].y = fdot2f(sv, u.y, acc[r].y);
                acc[r].z = fdot2f(sv, u.z, acc[r].z);
                acc[r].w = fdot2f(sv, u.w, acc[r].w);
            }
        }
        __syncthreads();                   // all s reads done; nb+qs8 regions free
        // partials: 32 KB split across nb_lds (kg 0-3) and qs8f (kg 4-7)
        float* baseW = (kg < 4) ? nb_lds : qs8f;
        const int kgm = kg & 3;
        #pragma unroll
        for (int r = 0; r < NB; ++r)
            *reinterpret_cast<float4*>(&baseW[(kgm * 8 + r) * 128 + c4i]) = acc[r];
        __syncthreads();

        {
            const int r = tid >> 5;
            float4 sum = make_float4(0.f, 0.f, 0.f, 0.f);
            #pragma unroll
            for (int g = 0; g < 8; ++g) {
                const float* bg = (g < 4) ? nb_lds : qs8f;
                const float4 p = *reinterpret_cast<const float4*>(
                    &bg[((g & 3) * 8 + r) * 128 + c4i]);
                sum.x += p.x; sum.y += p.y; sum.z += p.z; sum.w += p.w;
            }
            *reinterpret_cast<float4*>(out + (rb + r) * D + c4i) = sum;
        }
    }
}

} // namespace

extern "C" void kernel_launch(void* const* d_in, const int* in_sizes, int n_in,
                              void* d_out, int out_size, void* d_ws, size_t ws_size,
                              hipStream_t stream) {
    const float* center    = (const float*)d_in[0];
    const float* neighbors = (const float*)d_in[1];
    const float* WQ        = (const float*)d_in[2];
    const float* WK        = (const float*)d_in[3];
    const float* WV        = (const float*)d_in[4];
    const float* WO        = (const float*)d_in[5];
    float* outp            = (float*)d_out;

    const int B = in_sizes[0] / D;   // 8192

    unsigned* N2 = (unsigned*)d_ws;          // 64*1024 uint (256 KB)
    unsigned* M2 = N2 + 64 * 1024;           // 512*128 uint (256 KB)

    hipLaunchKernelGGL(k0_nm,   dim3(256),    dim3(256), 0, stream, WQ, WK, WV, WO, N2, M2);
    hipLaunchKernelGGL(k_fused, dim3(B / NB), dim3(256), 0, stream, center, neighbors, N2, M2, outp);
}

// Round 23
// 102.050 us; speedup vs baseline: 1.2201x; 1.0016x over previous
//
#include <hip/hip_runtime.h>
#include <hip/hip_bf16.h>
#include <math.h>

namespace {

constexpr int D  = 128;
constexpr int TN = 64;
constexpr int NB = 8;     // batches per fused block

typedef _Float16 h2 __attribute__((ext_vector_type(2)));

__device__ __forceinline__ unsigned pack_h2(float a, float b) {
    h2 v; v.x = (_Float16)a; v.y = (_Float16)b;
    return __builtin_bit_cast(unsigned, v);
}
__device__ __forceinline__ float2 unp_h2(unsigned u) {
    h2 v = __builtin_bit_cast(h2, u);
    return make_float2((float)v.x, (float)v.y);
}
__device__ __forceinline__ h2 bch2(unsigned u) { return __builtin_bit_cast(h2, u); }
__device__ __forceinline__ float fdot2f(unsigned a, unsigned b, float c) {
#if __has_builtin(__builtin_amdgcn_fdot2)
    return __builtin_amdgcn_fdot2(__builtin_bit_cast(h2, a),
                                  __builtin_bit_cast(h2, b), c, false);
#else
    const float2 fa = unp_h2(a), fb = unp_h2(b);
    return fmaf(fa.x, fb.x, fmaf(fa.y, fb.y, c));
#endif
}

// d_ws layout (both k-paired f16):
//   N2 [64][1024]  uint (pairs over k of N[128][1024])   256 KB
//   M2 [512][128]  uint (pairs over k of M[1024][128])   256 KB

// ---------------- K0: precompute N2 and M2 (k-paired f16, r20-proven) ----------------
__global__ __launch_bounds__(256)
void k0_nm(const float* __restrict__ WQ, const float* __restrict__ WK,
           const float* __restrict__ WV, const float* __restrict__ WO,
           unsigned* __restrict__ N2, unsigned* __restrict__ M2)
{
    const int t = blockIdx.x * 256 + threadIdx.x;   // 0..65535
    {   // N2[kk][col]: pair of N[2kk][col], N[2kk+1][col]
        const int kk = t >> 10, col = t & 1023;
        const int h = col >> 7, d = col & 127;
        const float* wq0 = WQ + (size_t)(2 * kk) * D + h * 16;
        const float* wq1 = wq0 + D;
        const float* wk  = WK + (size_t)d * D + h * 16;
        float a0 = 0.f, a1 = 0.f;
        #pragma unroll
        for (int j = 0; j < 16; ++j) {
            a0 = fmaf(wq0[j], wk[j], a0);
            a1 = fmaf(wq1[j], wk[j], a1);
        }
        N2[t] = pack_h2(0.25f * a0, 0.25f * a1);
    }
    {   // M2[kk][e]: pair of M[2kk][e], M[2kk+1][e];  k = h*128+d
        const int kk = t >> 7, e = t & 127;
        const int k0 = 2 * kk;
        const int h = k0 >> 7, d = k0 & 127;
        const float* wv0 = WV + (size_t)d * D + h * 16;
        const float* wv1 = wv0 + D;
        const float* wo  = WO + (size_t)(h * 16) * D + e;
        float b0 = 0.f, b1 = 0.f;
        #pragma unroll
        for (int j = 0; j < 16; ++j) {
            const float w_ = wo[(size_t)j * D];
            b0 = fmaf(wv0[j], w_, b0);
            b1 = fmaf(wv1[j], w_, b1);
        }
        M2[t] = pack_h2(b0, b1);
    }
}

// ---------------- fused: qk=c@N2 -> 8x attention -> out=s@M2 (r22 + DS diet) -------------
// LDS ~37.9 KB -> 4 blocks/CU.
__global__ __launch_bounds__(256, 2)
void k_fused(const float* __restrict__ center, const float* __restrict__ neighbors,
             const unsigned* __restrict__ N2, const unsigned* __restrict__ M2,
             float* __restrict__ out)
{
    __shared__ __align__(16) float nb_lds[TN * D / 2];  // 16 KB f16 tokens; uint2 slot (t<<5)|(fc^(t&7))
    __shared__ __align__(16) float qs8f[NB * 512];      // 16 KB f16: qk (rotated) -> s (k-paired linear)
    __shared__ __align__(16) unsigned c2u[NB * 64];     // 2 KB f16 k-paired center rows
    __shared__ __align__(16) unsigned Pu[TN * 12];      // 3 KB: P as duplicated f16 pairs {p,p}
    __shared__ float red_pc[8];

    const int tid = threadIdx.x;           // 0..255
    const int w   = tid >> 6;              // wave 0..3 (attention: owns heads 2w,2w+1)
    const int l   = tid & 63;
    const size_t rb = (size_t)blockIdx.x * NB;

    uint2* nbu  = (uint2*)nb_lds;
    uint2* qs8u = (uint2*)qs8f;

    // ---- stage c2 (k-paired f16) ----
    {
        const int r = tid >> 5, f = tid & 31;
        const float4 g = ((const float4*)(center + (rb + r) * (size_t)D))[f];
        c2u[r * 64 + 2 * f]     = pack_h2(g.x, g.y);
        c2u[r * 64 + 2 * f + 1] = pack_h2(g.z, g.w);
    }
    __syncthreads();                       // c2 visible

    // ================= k1-part: qk8 = c @ N (fdot2, kk-paired c reads) =================
    {
        const uint4* N2u4 = (const uint4*)N2;   // row kk = 256 uint4
        float4 acc[NB];
        #pragma unroll
        for (int r = 0; r < NB; ++r) acc[r] = make_float4(0.f, 0.f, 0.f, 0.f);

        #pragma unroll 2
        for (int kk2 = 0; kk2 < 32; ++kk2) {
            const int kk = 2 * kk2;
            const uint4 ua = N2u4[(size_t)kk * 256 + tid];        // 4 cols' k-pair (kk)
            const uint4 ub = N2u4[(size_t)(kk + 1) * 256 + tid];  // (kk+1)
            #pragma unroll
            for (int r = 0; r < NB; ++r) {
                const uint2 cp = *reinterpret_cast<const uint2*>(&c2u[r * 64 + kk]);
                acc[r].x = fdot2f(cp.x, ua.x, acc[r].x);
                acc[r].y = fdot2f(cp.x, ua.y, acc[r].y);
                acc[r].z = fdot2f(cp.x, ua.z, acc[r].z);
                acc[r].w = fdot2f(cp.x, ua.w, acc[r].w);
                acc[r].x = fdot2f(cp.y, ub.x, acc[r].x);
                acc[r].y = fdot2f(cp.y, ub.y, acc[r].y);
                acc[r].z = fdot2f(cp.y, ub.z, acc[r].z);
                acc[r].w = fdot2f(cp.y, ub.w, acc[r].w);
            }
        }
        const int fc = tid & 31;
        const int qslot = (tid & ~31) | (((fc & 7) << 2) | (fc >> 3));  // rotated qk layout
        #pragma unroll
        for (int r = 0; r < NB; ++r)
            qs8u[r * 256 + qslot] =
                make_uint2(pack_h2(acc[r].x, acc[r].y), pack_h2(acc[r].z, acc[r].w));
    }

    // ---- NOW load batch-0 nb into staging regs (not live across the GEMM above) ----
    float4 st[8];
    {
        const float4* g0 = (const float4*)(neighbors + rb * TN * D);
        #pragma unroll
        for (int i = 0; i < 8; ++i) st[i] = g0[i * 256 + tid];
    }
    __syncthreads();                       // qk visible

    // ================= per-batch attention loop =================
    #pragma unroll 1
    for (int bb = 0; bb < NB; ++bb) {
        // ---- commit staged nb registers -> f16 swizzled LDS ----
        #pragma unroll
        for (int i = 0; i < 8; ++i) {
            const int fi = i * 256 + tid;
            const int t  = fi >> 5;
            const int fc = fi & 31;
            nbu[(t << 5) | (fc ^ (t & 7))] =
                make_uint2(pack_h2(st[i].x, st[i].y), pack_h2(st[i].z, st[i].w));
        }
        __syncthreads();                   // nb staged

        // ---- issue next batch's nb loads; they fly during phases A-E ----
        if (bb + 1 < NB) {
            const float4* gn = (const float4*)(neighbors + (rb + bb + 1) * TN * D);
            #pragma unroll
            for (int i = 0; i < 8; ++i) st[i] = gn[i * 256 + tid];
        }

        const uint2*    nb2 = (const uint2*)nb_lds;
        const uint2*    qku = qs8u + bb * 256;
        const unsigned* cb2 = c2u + bb * 64;

        // ---- phase A: wave w scores all 64 tokens for heads 2w,2w+1; wave-local softmax ----
        const int tg = l & 15;
        const int q  = l >> 4;
        const int h0 = 2 * w;

        // hoist this lane's c-octave (16 uints) into regs: 4 uint4 LDS reads (was 16 scalar)
        unsigned cr[16];
        {
            const uint4* cb4 = (const uint4*)(cb2 + q * 16);
            *reinterpret_cast<uint4*>(&cr[0])  = cb4[0];
            *reinterpret_cast<uint4*>(&cr[4])  = cb4[1];
            *reinterpret_cast<uint4*>(&cr[8])  = cb4[2];
            *reinterpret_cast<uint4*>(&cr[12]) = cb4[3];
        }

        float sc0[4] = {0.f, 0.f, 0.f, 0.f};
        float sc1[4] = {0.f, 0.f, 0.f, 0.f};
        float s0a = 0.f, s0b = 0.f;
        #pragma unroll
        for (int jj = 0; jj < 8; ++jj) {
            const int rfc = (jj << 2) | q;     // rotated slot of fc=(q<<3)|jj
            const int fc  = (q << 3) | jj;
            const uint2 kv0p = qku[h0 * 32 + rfc];
            const uint2 kv1p = qku[(h0 + 1) * 32 + rfc];
            const unsigned cpa = cr[2 * jj], cpb = cr[2 * jj + 1];   // static idx (unrolled)
            s0a = fdot2f(cpa, kv0p.x, fdot2f(cpb, kv0p.y, s0a));
            s0b = fdot2f(cpa, kv1p.x, fdot2f(cpb, kv1p.y, s0b));
            #pragma unroll
            for (int k = 0; k < 4; ++k) {
                const int t = tg + (k << 4);
                const uint2 u = nb2[(t << 5) | (fc ^ (t & 7))];
                sc0[k] = fdot2f(u.x, kv0p.x, fdot2f(u.y, kv0p.y, sc0[k]));
                sc1[k] = fdot2f(u.x, kv1p.x, fdot2f(u.y, kv1p.y, sc1[k]));
            }
        }
        #pragma unroll
        for (int k = 0; k < 4; ++k) {
            sc0[k] += __shfl_xor(sc0[k], 16);  sc0[k] += __shfl_xor(sc0[k], 32);
            sc1[k] += __shfl_xor(sc1[k], 16);  sc1[k] += __shfl_xor(sc1[k], 32);
        }
        s0a += __shfl_xor(s0a, 16);  s0a += __shfl_xor(s0a, 32);
        s0b += __shfl_xor(s0b, 16);  s0b += __shfl_xor(s0b, 32);

        float m0 = fmaxf(fmaxf(sc0[0], sc0[1]), fmaxf(sc0[2], sc0[3]));
        float m1 = fmaxf(fmaxf(sc1[0], sc1[1]), fmaxf(sc1[2], sc1[3]));
        #pragma unroll
        for (int off = 8; off >= 1; off >>= 1) {
            m0 = fmaxf(m0, __shfl_xor(m0, off));
            m1 = fmaxf(m1, __shfl_xor(m1, off));
        }
        m0 = fmaxf(m0, s0a);
        m1 = fmaxf(m1, s0b);
        float e0v[4], e1v[4];
        float sum0 = 0.f, sum1 = 0.f;
        #pragma unroll
        for (int k = 0; k < 4; ++k) {
            e0v[k] = __expf(sc0[k] - m0);  sum0 += e0v[k];
            e1v[k] = __expf(sc1[k] - m1);  sum1 += e1v[k];
        }
        #pragma unroll
        for (int off = 8; off >= 1; off >>= 1) {
            sum0 += __shfl_xor(sum0, off);
            sum1 += __shfl_xor(sum1, off);
        }
        const float ec0 = __expf(s0a - m0);
        const float ec1 = __expf(s0b - m1);
        const float inv0 = 1.0f / (sum0 + ec0);
        const float inv1 = 1.0f / (sum1 + ec1);
        if (q == 0) {
            #pragma unroll
            for (int k = 0; k < 4; ++k) {
                const int t = tg + (k << 4);
                const float p0 = e0v[k] * inv0;
                const float p1 = e1v[k] * inv1;
                *reinterpret_cast<uint2*>(&Pu[t * 12 + h0]) =
                    make_uint2(pack_h2(p0, p0), pack_h2(p1, p1));
            }
            if (tg == 0) {
                red_pc[h0]     = ec0 * inv0;
                red_pc[h0 + 1] = ec1 * inv1;
            }
        }
        __syncthreads();   // bar: P complete

        // ---- phase D (pk_fma, r22-proven): wave w sums its 16 tokens ----
        const int hl  = l >> 5;
        const int fc2 = l & 31;
        h2 pk00 = {0, 0}, pk01 = {0, 0};
        h2 pk10 = {0, 0}, pk11 = {0, 0};
        h2 pk20 = {0, 0}, pk21 = {0, 0};
        h2 pk30 = {0, 0}, pk31 = {0, 0};
        #pragma unroll
        for (int tt = 0; tt < 16; ++tt) {
            const int t = w * 16 + tt;
            const uint2 u = nb2[(t << 5) | (fc2 ^ (t & 7))];
            const h2 u0 = bch2(u.x), u1 = bch2(u.y);
            const uint4 pp = *reinterpret_cast<const uint4*>(&Pu[t * 12 + hl * 4]);
            const h2 p0 = bch2(pp.x), p1 = bch2(pp.y), p2 = bch2(pp.z), p3 = bch2(pp.w);
            pk00 += p0 * u0;  pk01 += p0 * u1;
            pk10 += p1 * u0;  pk11 += p1 * u1;
            pk20 += p2 * u0;  pk21 += p2 * u1;
            pk30 += p3 * u0;  pk31 += p3 * u1;
        }
        {
            float4 pf;
            pf = make_float4((float)pk00.x, (float)pk00.y, (float)pk01.x, (float)pk01.y);
            ((float4*)nb_lds)[w * 256 + (hl * 4 + 0) * 32 + fc2] = pf;
            pf = make_float4((float)pk10.x, (float)pk10.y, (float)pk11.x, (float)pk11.y);
            ((float4*)nb_lds)[w * 256 + (hl * 4 + 1) * 32 + fc2] = pf;
            pf = make_float4((float)pk20.x, (float)pk20.y, (float)pk21.x, (float)pk21.y);
            ((float4*)nb_lds)[w * 256 + (hl * 4 + 2) * 32 + fc2] = pf;
            pf = make_float4((float)pk30.x, (float)pk30.y, (float)pk31.x, (float)pk31.y);
            ((float4*)nb_lds)[w * 256 + (hl * 4 + 3) * 32 + fc2] = pf;
        }
        __syncthreads();   // bar: partials ready

        // ---- phase E: combine partials + center seed; write s (f16 k-paired, linear) ----
        {
            const int hE = tid >> 5;
            const int fE = tid & 31;
            float4 sum = make_float4(0.f, 0.f, 0.f, 0.f);
            #pragma unroll
            for (int ww = 0; ww < 4; ++ww) {
                const float4 p = ((const float4*)nb_lds)[ww * 256 + hE * 32 + fE];
                sum.x += p.x; sum.y += p.y; sum.z += p.z; sum.w += p.w;
            }
            const float pc = red_pc[hE];
            const float2 ca = unp_h2(cb2[2 * fE]), cb = unp_h2(cb2[2 * fE + 1]);
            sum.x = fmaf(pc, ca.x, sum.x);
            sum.y = fmaf(pc, ca.y, sum.y);
            sum.z = fmaf(pc, cb.x, sum.z);
            sum.w = fmaf(pc, cb.y, sum.w);
            qs8u[bb * 256 + tid] =
                make_uint2(pack_h2(sum.x, sum.y), pack_h2(sum.z, sum.w));
        }
        __syncthreads();   // bar: partials consumed; next commit may overwrite nb
    }

    // ================= k3-part: out = s @ M (fdot2, kk-paired s reads) =================
    {
        const int cg = tid & 31;
        const int kg = tid >> 5;
        const int c4i = cg << 2;
        const int kb2 = kg << 6;           // kk base (64 pairs per k-split group)

        float4 acc[NB];
        #pragma unroll
        for (int r = 0; r < NB; ++r) acc[r] = make_float4(0.f, 0.f, 0.f, 0.f);

        const uint4* M2u4 = (const uint4*)M2;           // row kk = 32 uint4
        const unsigned* sp2 = (const unsigned*)qs8f;    // s pairs: [r*512 + kk]

        #pragma unroll 2
        for (int k4 = 0; k4 < 32; ++k4) {
            const int kk = kb2 + 2 * k4;
            const uint4 ua = M2u4[(size_t)kk * 32 + cg];
            const uint4 ub = M2u4[(size_t)(kk + 1) * 32 + cg];
            #pragma unroll
            for (int r = 0; r < NB; ++r) {
                const uint2 sv = *reinterpret_cast<const uint2*>(&sp2[r * 512 + kk]);
                acc[r].x = fdot2f(sv.x, ua.x, acc[r].x);
                acc[r].y = fdot2f(sv.x, ua.y, acc[r].y);
                acc[r].z = fdot2f(sv.x, ua.z, acc[r].z);
                acc[r].w = fdot2f(sv.x, ua.w, acc[r].w);
                acc[r].x = fdot2f(sv.y, ub.x, acc[r].x);
                acc[r].y = fdot2f(sv.y, ub.y, acc[r].y);
                acc[r].z = fdot2f(sv.y, ub.z, acc[r].z);
                acc[r].w = fdot2f(sv.y, ub.w, acc[r].w);
            }
        }
        __syncthreads();                   // all s reads done; nb+qs8 regions free
        // partials: 32 KB split across nb_lds (kg 0-3) and qs8f (kg 4-7)
        float* baseW = (kg < 4) ? nb_lds : qs8f;
        const int kgm = kg & 3;
        #pragma unroll
        for (int r = 0; r < NB; ++r)
            *reinterpret_cast<float4*>(&baseW[(kgm * 8 + r) * 128 + c4i]) = acc[r];
        __syncthreads();

        {
            const int r = tid >> 5;
            float4 sum = make_float4(0.f, 0.f, 0.f, 0.f);
            #pragma unroll
            for (int g = 0; g < 8; ++g) {
                const float* bg = (g < 4) ? nb_lds : qs8f;
                const float4 p = *reinterpret_cast<const float4*>(
                    &bg[((g & 3) * 8 + r) * 128 + c4i]);
                sum.x += p.x; sum.y += p.y; sum.z += p.z; sum.w += p.w;
            }
            *reinterpret_cast<float4*>(out + (rb + r) * D + c4i) = sum;
        }
    }
}

} // namespace

extern "C" void kernel_launch(void* const* d_in, const int* in_sizes, int n_in,
                              void* d_out, int out_size, void* d_ws, size_t ws_size,
                              hipStream_t stream) {
    const float* center    = (const float*)d_in[0];
    const float* neighbors = (const float*)d_in[1];
    const float* WQ        = (const float*)d_in[2];
    const float* WK        = (const float*)d_in[3];
    const float* WV        = (const float*)d_in[4];
    const float* WO        = (const float*)d_in[5];
    float* outp            = (float*)d_out;

    const int B = in_sizes[0] / D;   // 8192

    unsigned* N2 = (unsigned*)d_ws;          // 64*1024 uint (256 KB)
    unsigned* M2 = N2 + 64 * 1024;           // 512*128 uint (256 KB)

    hipLaunchKernelGGL(k0_nm,   dim3(256),    dim3(256), 0, stream, WQ, WK, WV, WO, N2, M2);
    hipLaunchKernelGGL(k_fused, dim3(B / NB), dim3(256), 0, stream, center, neighbors, N2, M2, outp);
}